// Round 1
// baseline (4236.193 us; speedup 1.0000x reference)
//
#include <hip/hip_runtime.h>
#include <math.h>

#define IN_F 67
#define F1   80   // H1*C1
#define NH1  10
#define NC1  8

// ---------------- init: bias-seeded accumulators ----------------
__global__ void k_init(float* __restrict__ out1, float* __restrict__ denom1,
                       float* __restrict__ denom2, float* __restrict__ out,
                       const float* __restrict__ b1, const float* __restrict__ b2,
                       int N) {
    int i = blockIdx.x * blockDim.x + threadIdx.x;
    int stride = gridDim.x * blockDim.x;
    for (int idx = i; idx < N * F1; idx += stride)
        out1[idx] = b1[idx % F1];
    for (int idx = i; idx < N * NH1; idx += stride)
        denom1[idx] = 0.f;
    for (int idx = i; idx < N; idx += stride) {
        denom2[idx] = 0.f;
        out[idx] = b2[0];
    }
}

// ---------------- layer 1 GEMM: h1 = x @ W1 ----------------
__global__ void k_gemm1(const float* __restrict__ x, const float* __restrict__ W,
                        float* __restrict__ h1, int N) {
    __shared__ float sW[IN_F * F1];  // 21.4 KB
    for (int i = threadIdx.x; i < IN_F * F1; i += blockDim.x) sW[i] = W[i];
    __syncthreads();
    int idx = blockIdx.x * blockDim.x + threadIdx.x;
    if (idx >= N * F1) return;
    int n = idx / F1;
    int f = idx - n * F1;
    const float* xr = x + n * IN_F;
    float acc = 0.f;
#pragma unroll
    for (int k = 0; k < IN_F; ++k) acc += xr[k] * sW[k * F1 + f];
    h1[idx] = acc;
}

// ---------------- layer 1 attention logits per node ----------------
__global__ void k_att1(const float* __restrict__ h1, const float* __restrict__ att_s,
                       const float* __restrict__ att_d, float* __restrict__ a_src,
                       float* __restrict__ a_dst, int N) {
    int idx = blockIdx.x * blockDim.x + threadIdx.x;  // n*NH1 + h
    if (idx >= N * NH1) return;
    int n = idx / NH1;
    int h = idx - n * NH1;
    const float* hr = h1 + n * F1 + h * NC1;
    float s = 0.f, d = 0.f;
#pragma unroll
    for (int c = 0; c < NC1; ++c) {
        float v = hr[c];
        s += v * att_s[h * NC1 + c];
        d += v * att_d[h * NC1 + c];
    }
    a_src[idx] = s;
    a_dst[idx] = d;
}

// ---------------- layer 1 edge pass 1: softmax denominators ----------------
__global__ void k_edge1a(const int* __restrict__ ei, const float* __restrict__ a_src,
                         const float* __restrict__ a_dst, float* __restrict__ denom,
                         int E, int EN) {
    int idx = blockIdx.x * blockDim.x + threadIdx.x;  // e*NH1 + h
    if (idx >= EN * NH1) return;
    int e = idx / NH1;
    int h = idx - e * NH1;
    int s, d;
    if (e < E) { s = ei[e]; d = ei[E + e]; } else { s = e - E; d = s; }
    float v = a_src[s * NH1 + h] + a_dst[d * NH1 + h];
    v = v > 0.f ? v : 0.2f * v;             // leaky_relu(0.2)
    atomicAdd(&denom[d * NH1 + h], __expf(v));
}

// ---------------- layer 1 edge pass 2: weighted scatter ----------------
__global__ void k_edge1b(const int* __restrict__ ei, const float* __restrict__ a_src,
                         const float* __restrict__ a_dst, const float* __restrict__ denom,
                         const float* __restrict__ h1, float* __restrict__ out1,
                         int E, int EN) {
    int idx = blockIdx.x * blockDim.x + threadIdx.x;  // e*NH1 + h
    if (idx >= EN * NH1) return;
    int e = idx / NH1;
    int h = idx - e * NH1;
    int s, d;
    if (e < E) { s = ei[e]; d = ei[E + e]; } else { s = e - E; d = s; }
    float v = a_src[s * NH1 + h] + a_dst[d * NH1 + h];
    v = v > 0.f ? v : 0.2f * v;
    float alpha = __expf(v) / denom[d * NH1 + h];
    const float* hs = h1 + s * F1 + h * NC1;
    float* od = out1 + d * F1 + h * NC1;
#pragma unroll
    for (int c = 0; c < NC1; ++c) atomicAdd(&od[c], hs[c] * alpha);
}

// ---------------- ELU + layer 2 projection (per node) ----------------
__global__ void k_l2proj(const float* __restrict__ out1, const float* __restrict__ W2,
                         const float* __restrict__ att_s2, const float* __restrict__ att_d2,
                         float* __restrict__ hl2, float* __restrict__ a_src2,
                         float* __restrict__ a_dst2, int N) {
    int n = blockIdx.x * blockDim.x + threadIdx.x;
    if (n >= N) return;
    float acc = 0.f;
#pragma unroll
    for (int f = 0; f < F1; ++f) {
        float v = out1[n * F1 + f];
        v = v > 0.f ? v : expm1f(v);        // elu(alpha=1)
        acc += v * W2[f];
    }
    hl2[n] = acc;
    a_src2[n] = acc * att_s2[0];
    a_dst2[n] = acc * att_d2[0];
}

// ---------------- layer 2 edge pass 1 ----------------
__global__ void k_edge2a(const int* __restrict__ ei, const float* __restrict__ a_src2,
                         const float* __restrict__ a_dst2, float* __restrict__ denom2,
                         int E, int EN) {
    int e = blockIdx.x * blockDim.x + threadIdx.x;
    if (e >= EN) return;
    int s, d;
    if (e < E) { s = ei[e]; d = ei[E + e]; } else { s = e - E; d = s; }
    float v = a_src2[s] + a_dst2[d];
    v = v > 0.f ? v : 0.2f * v;
    atomicAdd(&denom2[d], __expf(v));
}

// ---------------- layer 2 edge pass 2 ----------------
__global__ void k_edge2b(const int* __restrict__ ei, const float* __restrict__ a_src2,
                         const float* __restrict__ a_dst2, const float* __restrict__ denom2,
                         const float* __restrict__ hl2, float* __restrict__ out,
                         int E, int EN) {
    int e = blockIdx.x * blockDim.x + threadIdx.x;
    if (e >= EN) return;
    int s, d;
    if (e < E) { s = ei[e]; d = ei[E + e]; } else { s = e - E; d = s; }
    float v = a_src2[s] + a_dst2[d];
    v = v > 0.f ? v : 0.2f * v;
    float alpha = __expf(v) / denom2[d];
    atomicAdd(&out[d], hl2[s] * alpha);
}

extern "C" void kernel_launch(void* const* d_in, const int* in_sizes, int n_in,
                              void* d_out, int out_size, void* d_ws, size_t ws_size,
                              hipStream_t stream) {
    const float* x        = (const float*)d_in[0];
    const int*   ei       = (const int*)d_in[1];
    const float* W1       = (const float*)d_in[2];
    const float* att_src1 = (const float*)d_in[3];
    const float* att_dst1 = (const float*)d_in[4];
    const float* b1       = (const float*)d_in[5];
    const float* W2       = (const float*)d_in[6];
    const float* att_src2 = (const float*)d_in[7];
    const float* att_dst2 = (const float*)d_in[8];
    const float* b2       = (const float*)d_in[9];
    float* out = (float*)d_out;

    const int N  = in_sizes[0] / IN_F;   // 100000
    const int E  = in_sizes[1] / 2;      // 1600000
    const int EN = E + N;                // with self-loops

    // workspace layout (floats)
    float* ws     = (float*)d_ws;
    float* h1     = ws;                  // N*F1
    float* a_src1 = h1 + (size_t)N * F1; // N*NH1
    float* a_dst1 = a_src1 + (size_t)N * NH1;
    float* denom1 = a_dst1 + (size_t)N * NH1;
    float* out1   = denom1 + (size_t)N * NH1;   // N*F1
    float* hl2    = out1 + (size_t)N * F1;      // N
    float* a_src2 = hl2 + N;                    // N
    float* a_dst2 = a_src2 + N;                 // N
    float* denom2 = a_dst2 + N;                 // N

    const int B = 256;
    k_init<<<(N * F1 + B - 1) / B, B, 0, stream>>>(out1, denom1, denom2, out, b1, b2, N);
    k_gemm1<<<(N * F1 + B - 1) / B, B, 0, stream>>>(x, W1, h1, N);
    k_att1<<<(N * NH1 + B - 1) / B, B, 0, stream>>>(h1, att_src1, att_dst1, a_src1, a_dst1, N);
    k_edge1a<<<(EN * NH1 + B - 1) / B, B, 0, stream>>>(ei, a_src1, a_dst1, denom1, E, EN);
    k_edge1b<<<(EN * NH1 + B - 1) / B, B, 0, stream>>>(ei, a_src1, a_dst1, denom1, h1, out1, E, EN);
    k_l2proj<<<(N + B - 1) / B, B, 0, stream>>>(out1, W2, att_src2, att_dst2, hl2, a_src2, a_dst2, N);
    k_edge2a<<<(EN + B - 1) / B, B, 0, stream>>>(ei, a_src2, a_dst2, denom2, E, EN);
    k_edge2b<<<(EN + B - 1) / B, B, 0, stream>>>(ei, a_src2, a_dst2, denom2, hl2, out, E, EN);
}

// Round 2
// 596.242 us; speedup vs baseline: 7.1048x; 7.1048x over previous
//
#include <hip/hip_runtime.h>
#include <math.h>

#define IN_F 67
#define F1   80   // H1*C1
#define NH1  10
#define NC1  8

#define SCAN_T     256
#define SCAN_ELEMS 1024   // elements per scan block (4 per thread)

// ---------------- CSR build: degree histogram ----------------
__global__ void k_deg(const int* __restrict__ ei, int* __restrict__ deg, int E, int EN) {
    int e = blockIdx.x * blockDim.x + threadIdx.x;
    if (e >= EN) return;
    int d = (e < E) ? ei[E + e] : (e - E);
    atomicAdd(&deg[d], 1);
}

// ---------------- scan level 1: per-block sums ----------------
__global__ void k_scan1(const int* __restrict__ deg, int* __restrict__ bsum, int N) {
    __shared__ int sdata[SCAN_T];
    int base = blockIdx.x * SCAN_ELEMS;
    int sum = 0;
    for (int i = threadIdx.x; i < SCAN_ELEMS; i += SCAN_T) {
        int g = base + i;
        sum += (g < N) ? deg[g] : 0;
    }
    sdata[threadIdx.x] = sum;
    __syncthreads();
    for (int o = SCAN_T / 2; o > 0; o >>= 1) {
        if (threadIdx.x < o) sdata[threadIdx.x] += sdata[threadIdx.x + o];
        __syncthreads();
    }
    if (threadIdx.x == 0) bsum[blockIdx.x] = sdata[0];
}

// ---------------- scan level 2: exclusive scan of block sums (nb <= 256) ----
__global__ void k_scan2(int* __restrict__ bsum, int nb) {
    __shared__ int s[SCAN_T];
    int t = threadIdx.x;
    int v = (t < nb) ? bsum[t] : 0;
    s[t] = v;
    __syncthreads();
    for (int o = 1; o < SCAN_T; o <<= 1) {
        int u = (t >= o) ? s[t - o] : 0;
        __syncthreads();
        s[t] += u;
        __syncthreads();
    }
    if (t < nb) bsum[t] = s[t] - v;   // exclusive
}

// ---------------- scan level 3: per-element exclusive scan -> row ----------
__global__ void k_scan3(const int* __restrict__ deg, const int* __restrict__ bsum,
                        int* __restrict__ row, int N, int EN) {
    __shared__ int sdata[SCAN_T];
    int base = blockIdx.x * SCAN_ELEMS;
    int g0 = base + threadIdx.x * 4;
    int v[4];
    int s = 0;
#pragma unroll
    for (int j = 0; j < 4; ++j) {
        int g = g0 + j;
        v[j] = (g < N) ? deg[g] : 0;
        s += v[j];
    }
    sdata[threadIdx.x] = s;
    __syncthreads();
    for (int o = 1; o < SCAN_T; o <<= 1) {
        int u = (threadIdx.x >= o) ? sdata[threadIdx.x - o] : 0;
        __syncthreads();
        sdata[threadIdx.x] += u;
        __syncthreads();
    }
    int excl = sdata[threadIdx.x] - s + bsum[blockIdx.x];
#pragma unroll
    for (int j = 0; j < 4; ++j) {
        int g = g0 + j;
        if (g < N) { row[g] = excl; excl += v[j]; }
    }
    if (blockIdx.x == 0 && threadIdx.x == 0) row[N] = EN;
}

// ---------------- copy row -> cursor ----------------
__global__ void k_copy(const int* __restrict__ row, int* __restrict__ cursor, int N) {
    int i = blockIdx.x * blockDim.x + threadIdx.x;
    if (i < N) cursor[i] = row[i];
}

// ---------------- CSR fill: scatter src ids ----------------
__global__ void k_fill(const int* __restrict__ ei, int* __restrict__ cursor,
                       int* __restrict__ csr_src, int E, int EN) {
    int e = blockIdx.x * blockDim.x + threadIdx.x;
    if (e >= EN) return;
    int s, d;
    if (e < E) { s = ei[e]; d = ei[E + e]; } else { s = e - E; d = s; }
    int pos = atomicAdd(&cursor[d], 1);
    csr_src[pos] = s;
}

// ---------------- layer 1 GEMM: h1 = x @ W1 ----------------
__global__ void k_gemm1(const float* __restrict__ x, const float* __restrict__ W,
                        float* __restrict__ h1, int N) {
    __shared__ float sW[IN_F * F1];  // 21.4 KB
    for (int i = threadIdx.x; i < IN_F * F1; i += blockDim.x) sW[i] = W[i];
    __syncthreads();
    int idx = blockIdx.x * blockDim.x + threadIdx.x;
    if (idx >= N * F1) return;
    int n = idx / F1;
    int f = idx - n * F1;
    const float* xr = x + n * IN_F;
    float acc = 0.f;
#pragma unroll
    for (int k = 0; k < IN_F; ++k) acc += xr[k] * sW[k * F1 + f];
    h1[idx] = acc;
}

// ---------------- layer 1 attention logits per node ----------------
__global__ void k_att1(const float* __restrict__ h1, const float* __restrict__ att_s,
                       const float* __restrict__ att_d, float* __restrict__ a_src,
                       float* __restrict__ a_dst, int N) {
    int idx = blockIdx.x * blockDim.x + threadIdx.x;  // n*NH1 + h
    if (idx >= N * NH1) return;
    int n = idx / NH1;
    int h = idx - n * NH1;
    const float* hr = h1 + n * F1 + h * NC1;
    float s = 0.f, d = 0.f;
#pragma unroll
    for (int c = 0; c < NC1; ++c) {
        float v = hr[c];
        s += v * att_s[h * NC1 + c];
        d += v * att_d[h * NC1 + c];
    }
    a_src[idx] = s;
    a_dst[idx] = d;
}

// ---------------- layer 1 aggregation: one thread per (node, head) ---------
// out = (sum_e exp(lrelu(e)) * h1[src]) / (sum_e exp(lrelu(e))) + bias
__global__ void k_agg1(const int* __restrict__ row, const int* __restrict__ csr_src,
                       const float* __restrict__ a_src, const float* __restrict__ a_dst,
                       const float* __restrict__ h1, const float* __restrict__ b1,
                       float* __restrict__ out1, int N) {
    int idx = blockIdx.x * blockDim.x + threadIdx.x;  // n*NH1 + h
    if (idx >= N * NH1) return;
    int n = idx / NH1;
    int h = idx - n * NH1;
    int beg = row[n], end = row[n + 1];
    float ad = a_dst[idx];
    float den = 0.f;
    float4 num0 = {0.f, 0.f, 0.f, 0.f};
    float4 num1 = {0.f, 0.f, 0.f, 0.f};
    for (int i = beg; i < end; ++i) {
        int s = csr_src[i];
        float v = a_src[s * NH1 + h] + ad;
        v = v > 0.f ? v : 0.2f * v;            // leaky_relu(0.2)
        float w = __expf(v);
        den += w;
        const float4* hs = (const float4*)(h1 + s * F1 + h * NC1);
        float4 p0 = hs[0], p1 = hs[1];
        num0.x += w * p0.x; num0.y += w * p0.y; num0.z += w * p0.z; num0.w += w * p0.w;
        num1.x += w * p1.x; num1.y += w * p1.y; num1.z += w * p1.z; num1.w += w * p1.w;
    }
    float inv = 1.f / den;                      // deg >= 1 (self-loop)
    const float* bb = b1 + h * NC1;
    float* od = out1 + n * F1 + h * NC1;
    od[0] = num0.x * inv + bb[0];
    od[1] = num0.y * inv + bb[1];
    od[2] = num0.z * inv + bb[2];
    od[3] = num0.w * inv + bb[3];
    od[4] = num1.x * inv + bb[4];
    od[5] = num1.y * inv + bb[5];
    od[6] = num1.z * inv + bb[6];
    od[7] = num1.w * inv + bb[7];
}

// ---------------- ELU + layer 2 projection (per node) ----------------
__global__ void k_l2proj(const float* __restrict__ out1, const float* __restrict__ W2,
                         const float* __restrict__ att_s2, const float* __restrict__ att_d2,
                         float* __restrict__ hl2, float* __restrict__ a_src2,
                         float* __restrict__ a_dst2, int N) {
    int n = blockIdx.x * blockDim.x + threadIdx.x;
    if (n >= N) return;
    float acc = 0.f;
#pragma unroll
    for (int f = 0; f < F1; ++f) {
        float v = out1[n * F1 + f];
        v = v > 0.f ? v : expm1f(v);            // elu(alpha=1)
        acc += v * W2[f];
    }
    hl2[n] = acc;
    a_src2[n] = acc * att_s2[0];
    a_dst2[n] = acc * att_d2[0];
}

// ---------------- layer 2 aggregation: one thread per node ----------------
__global__ void k_agg2(const int* __restrict__ row, const int* __restrict__ csr_src,
                       const float* __restrict__ a_src2, const float* __restrict__ a_dst2,
                       const float* __restrict__ hl2, const float* __restrict__ b2,
                       float* __restrict__ out, int N) {
    int n = blockIdx.x * blockDim.x + threadIdx.x;
    if (n >= N) return;
    float ad = a_dst2[n];
    float den = 0.f, num = 0.f;
    int beg = row[n], end = row[n + 1];
    for (int i = beg; i < end; ++i) {
        int s = csr_src[i];
        float v = a_src2[s] + ad;
        v = v > 0.f ? v : 0.2f * v;
        float w = __expf(v);
        den += w;
        num += w * hl2[s];
    }
    out[n] = num / den + b2[0];
}

extern "C" void kernel_launch(void* const* d_in, const int* in_sizes, int n_in,
                              void* d_out, int out_size, void* d_ws, size_t ws_size,
                              hipStream_t stream) {
    const float* x        = (const float*)d_in[0];
    const int*   ei       = (const int*)d_in[1];
    const float* W1       = (const float*)d_in[2];
    const float* att_src1 = (const float*)d_in[3];
    const float* att_dst1 = (const float*)d_in[4];
    const float* b1       = (const float*)d_in[5];
    const float* W2       = (const float*)d_in[6];
    const float* att_src2 = (const float*)d_in[7];
    const float* att_dst2 = (const float*)d_in[8];
    const float* b2       = (const float*)d_in[9];
    float* out = (float*)d_out;

    const int N  = in_sizes[0] / IN_F;   // 100000
    const int E  = in_sizes[1] / 2;      // 1600000
    const int EN = E + N;                // with self-loops

    // workspace layout (4-byte slots)
    float* ws      = (float*)d_ws;
    float* h1      = ws;                               // N*F1
    float* a_src1  = h1 + (size_t)N * F1;              // N*NH1
    float* a_dst1  = a_src1 + (size_t)N * NH1;         // N*NH1
    float* out1    = a_dst1 + (size_t)N * NH1;         // N*F1
    float* hl2     = out1 + (size_t)N * F1;            // N
    float* a_src2  = hl2 + N;                          // N
    float* a_dst2  = a_src2 + N;                       // N
    int*   deg     = (int*)(a_dst2 + N);               // N (also reused as cursor)
    int*   row     = deg + N;                          // N+1
    int*   bsum    = row + (N + 1);                    // 256
    int*   csr_src = bsum + 256;                       // EN

    const int B = 256;
    const int nScanBlocks = (N + SCAN_ELEMS - 1) / SCAN_ELEMS;   // 98

    // ---- CSR build ----
    hipMemsetAsync(deg, 0, (size_t)N * sizeof(int), stream);
    k_deg  <<<(EN + B - 1) / B, B, 0, stream>>>(ei, deg, E, EN);
    k_scan1<<<nScanBlocks, SCAN_T, 0, stream>>>(deg, bsum, N);
    k_scan2<<<1, SCAN_T, 0, stream>>>(bsum, nScanBlocks);
    k_scan3<<<nScanBlocks, SCAN_T, 0, stream>>>(deg, bsum, row, N, EN);
    k_copy <<<(N + B - 1) / B, B, 0, stream>>>(row, deg, N);     // deg becomes cursor
    k_fill <<<(EN + B - 1) / B, B, 0, stream>>>(ei, deg, csr_src, E, EN);

    // ---- layer 1 ----
    k_gemm1<<<(N * F1 + B - 1) / B, B, 0, stream>>>(x, W1, h1, N);
    k_att1 <<<(N * NH1 + B - 1) / B, B, 0, stream>>>(h1, att_src1, att_dst1, a_src1, a_dst1, N);
    k_agg1 <<<(N * NH1 + 319) / 320, 320, 0, stream>>>(row, csr_src, a_src1, a_dst1, h1, b1, out1, N);

    // ---- layer 2 ----
    k_l2proj<<<(N + B - 1) / B, B, 0, stream>>>(out1, W2, att_src2, att_dst2, hl2, a_src2, a_dst2, N);
    k_agg2  <<<(N + B - 1) / B, B, 0, stream>>>(row, csr_src, a_src2, a_dst2, hl2, b2, out, N);
}

// Round 3
// 522.498 us; speedup vs baseline: 8.1076x; 1.1411x over previous
//
#include <hip/hip_runtime.h>
#include <math.h>

#define IN_F 67
#define F1   80   // H1*C1
#define NH1  10
#define NC1  8

#define SCAN_T     256
#define SCAN_ELEMS 1024   // elements per scan block (4 per thread)

#define BN 128            // nodes per GEMM block

// ---------------- CSR build: degree histogram ----------------
__global__ void k_deg(const int* __restrict__ ei, int* __restrict__ deg, int E, int EN) {
    int e = blockIdx.x * blockDim.x + threadIdx.x;
    if (e >= EN) return;
    int d = (e < E) ? ei[E + e] : (e - E);
    atomicAdd(&deg[d], 1);
}

// ---------------- scan level 1: per-block sums ----------------
__global__ void k_scan1(const int* __restrict__ deg, int* __restrict__ bsum, int N) {
    __shared__ int sdata[SCAN_T];
    int base = blockIdx.x * SCAN_ELEMS;
    int sum = 0;
    for (int i = threadIdx.x; i < SCAN_ELEMS; i += SCAN_T) {
        int g = base + i;
        sum += (g < N) ? deg[g] : 0;
    }
    sdata[threadIdx.x] = sum;
    __syncthreads();
    for (int o = SCAN_T / 2; o > 0; o >>= 1) {
        if (threadIdx.x < o) sdata[threadIdx.x] += sdata[threadIdx.x + o];
        __syncthreads();
    }
    if (threadIdx.x == 0) bsum[blockIdx.x] = sdata[0];
}

// ---------------- scan level 2: exclusive scan of block sums (nb <= 256) ----
__global__ void k_scan2(int* __restrict__ bsum, int nb) {
    __shared__ int s[SCAN_T];
    int t = threadIdx.x;
    int v = (t < nb) ? bsum[t] : 0;
    s[t] = v;
    __syncthreads();
    for (int o = 1; o < SCAN_T; o <<= 1) {
        int u = (t >= o) ? s[t - o] : 0;
        __syncthreads();
        s[t] += u;
        __syncthreads();
    }
    if (t < nb) bsum[t] = s[t] - v;   // exclusive
}

// ---------------- scan level 3: per-element exclusive scan -> row ----------
__global__ void k_scan3(const int* __restrict__ deg, const int* __restrict__ bsum,
                        int* __restrict__ row, int N, int EN) {
    __shared__ int sdata[SCAN_T];
    int base = blockIdx.x * SCAN_ELEMS;
    int g0 = base + threadIdx.x * 4;
    int v[4];
    int s = 0;
#pragma unroll
    for (int j = 0; j < 4; ++j) {
        int g = g0 + j;
        v[j] = (g < N) ? deg[g] : 0;
        s += v[j];
    }
    sdata[threadIdx.x] = s;
    __syncthreads();
    for (int o = 1; o < SCAN_T; o <<= 1) {
        int u = (threadIdx.x >= o) ? sdata[threadIdx.x - o] : 0;
        __syncthreads();
        sdata[threadIdx.x] += u;
        __syncthreads();
    }
    int excl = sdata[threadIdx.x] - s + bsum[blockIdx.x];
#pragma unroll
    for (int j = 0; j < 4; ++j) {
        int g = g0 + j;
        if (g < N) { row[g] = excl; excl += v[j]; }
    }
    if (blockIdx.x == 0 && threadIdx.x == 0) row[N] = EN;
}

// ---------------- copy row -> cursor ----------------
__global__ void k_copy(const int* __restrict__ row, int* __restrict__ cursor, int N) {
    int i = blockIdx.x * blockDim.x + threadIdx.x;
    if (i < N) cursor[i] = row[i];
}

// ---------------- CSR fill: scatter src ids ----------------
__global__ void k_fill(const int* __restrict__ ei, int* __restrict__ cursor,
                       int* __restrict__ csr_src, int E, int EN) {
    int e = blockIdx.x * blockDim.x + threadIdx.x;
    if (e >= EN) return;
    int s, d;
    if (e < E) { s = ei[e]; d = ei[E + e]; } else { s = e - E; d = s; }
    int pos = atomicAdd(&cursor[d], 1);
    csr_src[pos] = s;
}

// ---------------- layer 1: fused GEMM + attention logits ----------------
// h1 = x @ W1 ; a_src/a_dst = head-wise dots with att vectors.
// 256 threads = 16 tx * 16 ty. Each thread: 8 nodes (ty*8+i) x 5 cols (tx*5+j).
__global__ __launch_bounds__(256, 2)
void k_gemm1(const float* __restrict__ x, const float* __restrict__ W,
             const float* __restrict__ att_s, const float* __restrict__ att_d,
             float* __restrict__ h1, float* __restrict__ a_src,
             float* __restrict__ a_dst, int N) {
    __shared__ float sW[IN_F * F1];       // 21440 B, flat == W layout
    __shared__ float sbuf[BN * 81];       // 41472 B; x-phase stride 69, h-phase stride 81

    const int tid = threadIdx.x;
    const int node0 = blockIdx.x * BN;

    // stage W (coalesced, no pad needed: read pattern 5*tx mod 32 is conflict-free)
    for (int i = tid; i < IN_F * F1; i += 256) sW[i] = W[i];
    // stage x tile transposed-free: sbuf[n*69 + k]
    for (int i = tid; i < BN * IN_F; i += 256) {
        int n = i / IN_F;
        int k = i - n * IN_F;
        int gn = node0 + n;
        sbuf[n * 69 + k] = (gn < N) ? x[gn * IN_F + k] : 0.f;
    }
    __syncthreads();

    const int tx = tid & 15, ty = tid >> 4;
    float acc[8][5];
#pragma unroll
    for (int i = 0; i < 8; ++i)
#pragma unroll
        for (int j = 0; j < 5; ++j) acc[i][j] = 0.f;

    const float* sxp = sbuf + ty * 8 * 69;
    const float* swp = sW + tx * 5;
    for (int k = 0; k < IN_F; ++k) {
        float b0 = swp[k * F1 + 0];
        float b1 = swp[k * F1 + 1];
        float b2 = swp[k * F1 + 2];
        float b3 = swp[k * F1 + 3];
        float b4 = swp[k * F1 + 4];
#pragma unroll
        for (int i = 0; i < 8; ++i) {
            float a = sxp[i * 69 + k];
            acc[i][0] += a * b0;
            acc[i][1] += a * b1;
            acc[i][2] += a * b2;
            acc[i][3] += a * b3;
            acc[i][4] += a * b4;
        }
    }

    __syncthreads();   // all x reads done before sbuf is repurposed
    // write h tile to LDS, stride 81 (5*tx mod 32 distinct -> conflict-free)
#pragma unroll
    for (int i = 0; i < 8; ++i)
#pragma unroll
        for (int j = 0; j < 5; ++j)
            sbuf[(ty * 8 + i) * 81 + tx * 5 + j] = acc[i][j];
    __syncthreads();

    // coalesced h1 write-out
    for (int idx = tid; idx < BN * F1; idx += 256) {
        int n = idx / F1;
        int c = idx - n * F1;
        int gn = node0 + n;
        if (gn < N) h1[gn * F1 + c] = sbuf[n * 81 + c];
    }
    // attention logits: 1280 tasks, 5 per thread
    for (int t = tid; t < BN * NH1; t += 256) {
        int n = t / NH1;
        int h = t - n * NH1;
        int gn = node0 + n;
        if (gn < N) {
            const float* hr = sbuf + n * 81 + h * NC1;
            float s = 0.f, d = 0.f;
#pragma unroll
            for (int c = 0; c < NC1; ++c) {
                float v = hr[c];
                s += v * att_s[h * NC1 + c];
                d += v * att_d[h * NC1 + c];
            }
            a_src[gn * NH1 + h] = s;
            a_dst[gn * NH1 + h] = d;
        }
    }
}

// ---------------- layer 1 aggregation: one thread per (node, head) ---------
// out = (sum_e exp(lrelu(e)) * h1[src]) / (sum_e exp(lrelu(e))) + bias
__global__ void k_agg1(const int* __restrict__ row, const int* __restrict__ csr_src,
                       const float* __restrict__ a_src, const float* __restrict__ a_dst,
                       const float* __restrict__ h1, const float* __restrict__ b1,
                       float* __restrict__ out1, int N) {
    int idx = blockIdx.x * blockDim.x + threadIdx.x;  // n*NH1 + h
    if (idx >= N * NH1) return;
    int n = idx / NH1;
    int h = idx - n * NH1;
    int beg = row[n], end = row[n + 1];
    float ad = a_dst[idx];
    float den = 0.f;
    float4 num0 = {0.f, 0.f, 0.f, 0.f};
    float4 num1 = {0.f, 0.f, 0.f, 0.f};
    int i = beg;
    // 4-wide unroll: batch independent gather chains for MLP
    for (; i + 3 < end; i += 4) {
        int s0 = csr_src[i], s1 = csr_src[i + 1], s2 = csr_src[i + 2], s3 = csr_src[i + 3];
        float v0 = a_src[s0 * NH1 + h] + ad;
        float v1 = a_src[s1 * NH1 + h] + ad;
        float v2 = a_src[s2 * NH1 + h] + ad;
        float v3 = a_src[s3 * NH1 + h] + ad;
        const float4* q0 = (const float4*)(h1 + s0 * F1 + h * NC1);
        const float4* q1 = (const float4*)(h1 + s1 * F1 + h * NC1);
        const float4* q2 = (const float4*)(h1 + s2 * F1 + h * NC1);
        const float4* q3 = (const float4*)(h1 + s3 * F1 + h * NC1);
        float4 p00 = q0[0], p01 = q0[1];
        float4 p10 = q1[0], p11 = q1[1];
        float4 p20 = q2[0], p21 = q2[1];
        float4 p30 = q3[0], p31 = q3[1];
        v0 = v0 > 0.f ? v0 : 0.2f * v0;
        v1 = v1 > 0.f ? v1 : 0.2f * v1;
        v2 = v2 > 0.f ? v2 : 0.2f * v2;
        v3 = v3 > 0.f ? v3 : 0.2f * v3;
        float w0 = __expf(v0), w1 = __expf(v1), w2 = __expf(v2), w3 = __expf(v3);
        den += (w0 + w1) + (w2 + w3);
        num0.x += w0 * p00.x + w1 * p10.x + w2 * p20.x + w3 * p30.x;
        num0.y += w0 * p00.y + w1 * p10.y + w2 * p20.y + w3 * p30.y;
        num0.z += w0 * p00.z + w1 * p10.z + w2 * p20.z + w3 * p30.z;
        num0.w += w0 * p00.w + w1 * p10.w + w2 * p20.w + w3 * p30.w;
        num1.x += w0 * p01.x + w1 * p11.x + w2 * p21.x + w3 * p31.x;
        num1.y += w0 * p01.y + w1 * p11.y + w2 * p21.y + w3 * p31.y;
        num1.z += w0 * p01.z + w1 * p11.z + w2 * p21.z + w3 * p31.z;
        num1.w += w0 * p01.w + w1 * p11.w + w2 * p21.w + w3 * p31.w;
    }
    for (; i < end; ++i) {
        int s = csr_src[i];
        float v = a_src[s * NH1 + h] + ad;
        v = v > 0.f ? v : 0.2f * v;
        float w = __expf(v);
        den += w;
        const float4* hs = (const float4*)(h1 + s * F1 + h * NC1);
        float4 p0 = hs[0], p1 = hs[1];
        num0.x += w * p0.x; num0.y += w * p0.y; num0.z += w * p0.z; num0.w += w * p0.w;
        num1.x += w * p1.x; num1.y += w * p1.y; num1.z += w * p1.z; num1.w += w * p1.w;
    }
    float inv = 1.f / den;                      // deg >= 1 (self-loop)
    const float* bb = b1 + h * NC1;
    float* od = out1 + n * F1 + h * NC1;
    od[0] = num0.x * inv + bb[0];
    od[1] = num0.y * inv + bb[1];
    od[2] = num0.z * inv + bb[2];
    od[3] = num0.w * inv + bb[3];
    od[4] = num1.x * inv + bb[4];
    od[5] = num1.y * inv + bb[5];
    od[6] = num1.z * inv + bb[6];
    od[7] = num1.w * inv + bb[7];
}

// ---------------- ELU + layer 2 projection (per node) ----------------
__global__ void k_l2proj(const float* __restrict__ out1, const float* __restrict__ W2,
                         const float* __restrict__ att_s2, const float* __restrict__ att_d2,
                         float* __restrict__ hl2, float* __restrict__ a_src2,
                         float* __restrict__ a_dst2, int N) {
    int n = blockIdx.x * blockDim.x + threadIdx.x;
    if (n >= N) return;
    float acc = 0.f;
#pragma unroll
    for (int f = 0; f < F1; ++f) {
        float v = out1[n * F1 + f];
        v = v > 0.f ? v : expm1f(v);            // elu(alpha=1)
        acc += v * W2[f];
    }
    hl2[n] = acc;
    a_src2[n] = acc * att_s2[0];
    a_dst2[n] = acc * att_d2[0];
}

// ---------------- layer 2 aggregation: one thread per node ----------------
__global__ void k_agg2(const int* __restrict__ row, const int* __restrict__ csr_src,
                       const float* __restrict__ a_src2, const float* __restrict__ a_dst2,
                       const float* __restrict__ hl2, const float* __restrict__ b2,
                       float* __restrict__ out, int N) {
    int n = blockIdx.x * blockDim.x + threadIdx.x;
    if (n >= N) return;
    float ad = a_dst2[n];
    float den = 0.f, num = 0.f;
    int beg = row[n], end = row[n + 1];
    int i = beg;
    for (; i + 3 < end; i += 4) {
        int s0 = csr_src[i], s1 = csr_src[i + 1], s2 = csr_src[i + 2], s3 = csr_src[i + 3];
        float v0 = a_src2[s0] + ad, v1 = a_src2[s1] + ad;
        float v2 = a_src2[s2] + ad, v3 = a_src2[s3] + ad;
        float g0 = hl2[s0], g1 = hl2[s1], g2 = hl2[s2], g3 = hl2[s3];
        v0 = v0 > 0.f ? v0 : 0.2f * v0;
        v1 = v1 > 0.f ? v1 : 0.2f * v1;
        v2 = v2 > 0.f ? v2 : 0.2f * v2;
        v3 = v3 > 0.f ? v3 : 0.2f * v3;
        float w0 = __expf(v0), w1 = __expf(v1), w2 = __expf(v2), w3 = __expf(v3);
        den += (w0 + w1) + (w2 + w3);
        num += (w0 * g0 + w1 * g1) + (w2 * g2 + w3 * g3);
    }
    for (; i < end; ++i) {
        int s = csr_src[i];
        float v = a_src2[s] + ad;
        v = v > 0.f ? v : 0.2f * v;
        float w = __expf(v);
        den += w;
        num += w * hl2[s];
    }
    out[n] = num / den + b2[0];
}

extern "C" void kernel_launch(void* const* d_in, const int* in_sizes, int n_in,
                              void* d_out, int out_size, void* d_ws, size_t ws_size,
                              hipStream_t stream) {
    const float* x        = (const float*)d_in[0];
    const int*   ei       = (const int*)d_in[1];
    const float* W1       = (const float*)d_in[2];
    const float* att_src1 = (const float*)d_in[3];
    const float* att_dst1 = (const float*)d_in[4];
    const float* b1       = (const float*)d_in[5];
    const float* W2       = (const float*)d_in[6];
    const float* att_src2 = (const float*)d_in[7];
    const float* att_dst2 = (const float*)d_in[8];
    const float* b2       = (const float*)d_in[9];
    float* out = (float*)d_out;

    const int N  = in_sizes[0] / IN_F;   // 100000
    const int E  = in_sizes[1] / 2;      // 1600000
    const int EN = E + N;                // with self-loops

    // workspace layout (4-byte slots)
    float* ws      = (float*)d_ws;
    float* h1      = ws;                               // N*F1
    float* a_src1  = h1 + (size_t)N * F1;              // N*NH1
    float* a_dst1  = a_src1 + (size_t)N * NH1;         // N*NH1
    float* out1    = a_dst1 + (size_t)N * NH1;         // N*F1
    float* hl2     = out1 + (size_t)N * F1;            // N
    float* a_src2  = hl2 + N;                          // N
    float* a_dst2  = a_src2 + N;                       // N
    int*   deg     = (int*)(a_dst2 + N);               // N (also reused as cursor)
    int*   row     = deg + N;                          // N+1
    int*   bsum    = row + (N + 1);                    // 256
    int*   csr_src = bsum + 256;                       // EN

    const int B = 256;
    const int nScanBlocks = (N + SCAN_ELEMS - 1) / SCAN_ELEMS;   // 98

    // ---- CSR build ----
    hipMemsetAsync(deg, 0, (size_t)N * sizeof(int), stream);
    k_deg  <<<(EN + B - 1) / B, B, 0, stream>>>(ei, deg, E, EN);
    k_scan1<<<nScanBlocks, SCAN_T, 0, stream>>>(deg, bsum, N);
    k_scan2<<<1, SCAN_T, 0, stream>>>(bsum, nScanBlocks);
    k_scan3<<<nScanBlocks, SCAN_T, 0, stream>>>(deg, bsum, row, N, EN);
    k_copy <<<(N + B - 1) / B, B, 0, stream>>>(row, deg, N);     // deg becomes cursor
    k_fill <<<(EN + B - 1) / B, B, 0, stream>>>(ei, deg, csr_src, E, EN);

    // ---- layer 1 ----
    k_gemm1<<<(N + BN - 1) / BN, 256, 0, stream>>>(x, W1, att_src1, att_dst1,
                                                   h1, a_src1, a_dst1, N);
    k_agg1 <<<(N * NH1 + B - 1) / B, B, 0, stream>>>(row, csr_src, a_src1, a_dst1, h1, b1, out1, N);

    // ---- layer 2 ----
    k_l2proj<<<(N + B - 1) / B, B, 0, stream>>>(out1, W2, att_src2, att_dst2, hl2, a_src2, a_dst2, N);
    k_agg2  <<<(N + B - 1) / B, B, 0, stream>>>(row, csr_src, a_src2, a_dst2, hl2, b2, out, N);
}

// Round 4
// 369.344 us; speedup vs baseline: 11.4695x; 1.4147x over previous
//
#include <hip/hip_runtime.h>
#include <math.h>

#define IN_F 67
#define F1   80   // H1*C1
#define NH1  10
#define NC1  8

#define SCAN_T     256
#define SCAN_ELEMS 1024   // elements per scan block (4 per thread)

#define BN  128           // nodes per GEMM block
#define NPB 25            // nodes per agg1 block (25*10 = 250 active threads)

typedef _Float16 h16;
typedef h16 h16x2 __attribute__((ext_vector_type(2)));
typedef h16 h16x8 __attribute__((ext_vector_type(8)));

// ---------------- CSR build: degree histogram + within-segment position ----
__global__ void k_degpos(const int* __restrict__ ei, int* __restrict__ deg,
                         int* __restrict__ pos, int E, int EN) {
    int e = blockIdx.x * blockDim.x + threadIdx.x;
    if (e >= EN) return;
    int d = (e < E) ? ei[E + e] : (e - E);
    pos[e] = atomicAdd(&deg[d], 1);
}

// ---------------- scan level 1: per-block sums ----------------
__global__ void k_scan1(const int* __restrict__ deg, int* __restrict__ bsum, int N) {
    __shared__ int sdata[SCAN_T];
    int base = blockIdx.x * SCAN_ELEMS;
    int sum = 0;
    for (int i = threadIdx.x; i < SCAN_ELEMS; i += SCAN_T) {
        int g = base + i;
        sum += (g < N) ? deg[g] : 0;
    }
    sdata[threadIdx.x] = sum;
    __syncthreads();
    for (int o = SCAN_T / 2; o > 0; o >>= 1) {
        if (threadIdx.x < o) sdata[threadIdx.x] += sdata[threadIdx.x + o];
        __syncthreads();
    }
    if (threadIdx.x == 0) bsum[blockIdx.x] = sdata[0];
}

// ---------------- scan level 2: exclusive scan of block sums (nb <= 256) ----
__global__ void k_scan2(int* __restrict__ bsum, int nb) {
    __shared__ int s[SCAN_T];
    int t = threadIdx.x;
    int v = (t < nb) ? bsum[t] : 0;
    s[t] = v;
    __syncthreads();
    for (int o = 1; o < SCAN_T; o <<= 1) {
        int u = (t >= o) ? s[t - o] : 0;
        __syncthreads();
        s[t] += u;
        __syncthreads();
    }
    if (t < nb) bsum[t] = s[t] - v;   // exclusive
}

// ---------------- scan level 3: per-element exclusive scan -> row ----------
__global__ void k_scan3(const int* __restrict__ deg, const int* __restrict__ bsum,
                        int* __restrict__ row, int N, int EN) {
    __shared__ int sdata[SCAN_T];
    int base = blockIdx.x * SCAN_ELEMS;
    int g0 = base + threadIdx.x * 4;
    int v[4];
    int s = 0;
#pragma unroll
    for (int j = 0; j < 4; ++j) {
        int g = g0 + j;
        v[j] = (g < N) ? deg[g] : 0;
        s += v[j];
    }
    sdata[threadIdx.x] = s;
    __syncthreads();
    for (int o = 1; o < SCAN_T; o <<= 1) {
        int u = (threadIdx.x >= o) ? sdata[threadIdx.x - o] : 0;
        __syncthreads();
        sdata[threadIdx.x] += u;
        __syncthreads();
    }
    int excl = sdata[threadIdx.x] - s + bsum[blockIdx.x];
#pragma unroll
    for (int j = 0; j < 4; ++j) {
        int g = g0 + j;
        if (g < N) { row[g] = excl; excl += v[j]; }
    }
    if (blockIdx.x == 0 && threadIdx.x == 0) row[N] = EN;
}

// ---------------- CSR fill: atomic-free, XCD-partitioned by dst range ------
// Block b handles dst in [ (b&7)*range, ... ). Under round-robin dispatch all
// writers of a csr_src region sit on one XCD -> L2 write-combining ->
// full-line writebacks instead of 64B-per-4B scatter. Locality-only heuristic.
__global__ void k_fill(const int* __restrict__ ei, const int* __restrict__ row,
                       const int* __restrict__ pos, int* __restrict__ csr_src,
                       int E, int EN, int N, int nchunk) {
    int xcd = blockIdx.x & 7;
    int cb  = blockIdx.x >> 3;
    int range = (N + 7) >> 3;
    int lo = xcd * range;
    int hi = lo + range;            // N not pow2-critical: d < N always
    int stride = nchunk * blockDim.x;
    for (int e = cb * blockDim.x + threadIdx.x; e < EN; e += stride) {
        int s, d;
        if (e < E) { d = ei[E + e]; s = ei[e]; } else { d = e - E; s = d; }
        if (d >= lo && d < hi) {
            csr_src[row[d] + pos[e]] = s;
        }
    }
}

// ---------------- layer 1: fused GEMM + attention logits (h1 stored fp16) --
__global__ __launch_bounds__(256, 2)
void k_gemm1(const float* __restrict__ x, const float* __restrict__ W,
             const float* __restrict__ att_s, const float* __restrict__ att_d,
             h16* __restrict__ h1h, float* __restrict__ a_src,
             float* __restrict__ a_dst, int N) {
    __shared__ float sW[IN_F * F1];       // 21440 B
    __shared__ float sbuf[BN * 81];       // x-phase stride 69, h-phase stride 81

    const int tid = threadIdx.x;
    const int node0 = blockIdx.x * BN;

    for (int i = tid; i < IN_F * F1; i += 256) sW[i] = W[i];
    for (int i = tid; i < BN * IN_F; i += 256) {
        int n = i / IN_F;
        int k = i - n * IN_F;
        int gn = node0 + n;
        sbuf[n * 69 + k] = (gn < N) ? x[gn * IN_F + k] : 0.f;
    }
    __syncthreads();

    const int tx = tid & 15, ty = tid >> 4;
    float acc[8][5];
#pragma unroll
    for (int i = 0; i < 8; ++i)
#pragma unroll
        for (int j = 0; j < 5; ++j) acc[i][j] = 0.f;

    const float* sxp = sbuf + ty * 8 * 69;
    const float* swp = sW + tx * 5;
    for (int k = 0; k < IN_F; ++k) {
        float b0 = swp[k * F1 + 0];
        float b1 = swp[k * F1 + 1];
        float b2 = swp[k * F1 + 2];
        float b3 = swp[k * F1 + 3];
        float b4 = swp[k * F1 + 4];
#pragma unroll
        for (int i = 0; i < 8; ++i) {
            float a = sxp[i * 69 + k];
            acc[i][0] += a * b0;
            acc[i][1] += a * b1;
            acc[i][2] += a * b2;
            acc[i][3] += a * b3;
            acc[i][4] += a * b4;
        }
    }

    __syncthreads();
#pragma unroll
    for (int i = 0; i < 8; ++i)
#pragma unroll
        for (int j = 0; j < 5; ++j)
            sbuf[(ty * 8 + i) * 81 + tx * 5 + j] = acc[i][j];
    __syncthreads();

    // h1 write-out as fp16 pairs (coalesced 4B stores)
    for (int idx = tid; idx < BN * (F1 / 2); idx += 256) {
        int n = idx / (F1 / 2);
        int p = idx - n * (F1 / 2);
        int gn = node0 + n;
        if (gn < N) {
            h16x2 v;
            v.x = (h16)sbuf[n * 81 + 2 * p];
            v.y = (h16)sbuf[n * 81 + 2 * p + 1];
            *(h16x2*)(h1h + (size_t)gn * F1 + 2 * p) = v;
        }
    }
    // attention logits from fp32 tile
    for (int t = tid; t < BN * NH1; t += 256) {
        int n = t / NH1;
        int h = t - n * NH1;
        int gn = node0 + n;
        if (gn < N) {
            const float* hr = sbuf + n * 81 + h * NC1;
            float s = 0.f, d = 0.f;
#pragma unroll
            for (int c = 0; c < NC1; ++c) {
                float v = hr[c];
                s += v * att_s[h * NC1 + c];
                d += v * att_d[h * NC1 + c];
            }
            a_src[gn * NH1 + h] = s;
            a_dst[gn * NH1 + h] = d;
        }
    }
}

// ---------------- layer 1 aggregation FUSED with ELU + layer-2 projection --
// thread (n,h) aggregates 8 channels, applies bias+elu, dots with its W2
// slice; 10 head-partials reduced in LDS -> hl2 / a_src2 / a_dst2 per node.
// out1 is never materialized.
__global__ __launch_bounds__(256)
void k_agg1(const int* __restrict__ row, const int* __restrict__ csr_src,
            const float* __restrict__ a_src, const float* __restrict__ a_dst,
            const h16* __restrict__ h1h, const float* __restrict__ b1,
            const float* __restrict__ W2, const float* __restrict__ att_s2,
            const float* __restrict__ att_d2, float* __restrict__ hl2,
            float* __restrict__ a_src2, float* __restrict__ a_dst2, int N) {
    __shared__ float spart[256];
    const int tid = threadIdx.x;
    const int node0 = blockIdx.x * NPB;

    float partial = 0.f;
    if (tid < NPB * NH1) {
        int n_l = tid / NH1;
        int h = tid - n_l * NH1;
        int n = node0 + n_l;
        if (n < N) {
            int beg = row[n], end = row[n + 1];
            float ad = a_dst[n * NH1 + h];
            float den = 0.f;
            float num[NC1];
#pragma unroll
            for (int c = 0; c < NC1; ++c) num[c] = 0.f;

            int i = beg;
            for (; i + 3 < end; i += 4) {
                int s0 = csr_src[i], s1 = csr_src[i + 1];
                int s2 = csr_src[i + 2], s3 = csr_src[i + 3];
                h16x8 q0 = *(const h16x8*)(h1h + (size_t)s0 * F1 + h * NC1);
                h16x8 q1 = *(const h16x8*)(h1h + (size_t)s1 * F1 + h * NC1);
                h16x8 q2 = *(const h16x8*)(h1h + (size_t)s2 * F1 + h * NC1);
                h16x8 q3 = *(const h16x8*)(h1h + (size_t)s3 * F1 + h * NC1);
                float v0 = a_src[s0 * NH1 + h] + ad;
                float v1 = a_src[s1 * NH1 + h] + ad;
                float v2 = a_src[s2 * NH1 + h] + ad;
                float v3 = a_src[s3 * NH1 + h] + ad;
                v0 = v0 > 0.f ? v0 : 0.2f * v0;
                v1 = v1 > 0.f ? v1 : 0.2f * v1;
                v2 = v2 > 0.f ? v2 : 0.2f * v2;
                v3 = v3 > 0.f ? v3 : 0.2f * v3;
                float w0 = __expf(v0), w1 = __expf(v1);
                float w2 = __expf(v2), w3 = __expf(v3);
                den += (w0 + w1) + (w2 + w3);
#pragma unroll
                for (int c = 0; c < NC1; ++c)
                    num[c] += w0 * (float)q0[c] + w1 * (float)q1[c]
                            + w2 * (float)q2[c] + w3 * (float)q3[c];
            }
            for (; i < end; ++i) {
                int s = csr_src[i];
                h16x8 q = *(const h16x8*)(h1h + (size_t)s * F1 + h * NC1);
                float v = a_src[s * NH1 + h] + ad;
                v = v > 0.f ? v : 0.2f * v;
                float w = __expf(v);
                den += w;
#pragma unroll
                for (int c = 0; c < NC1; ++c) num[c] += w * (float)q[c];
            }
            float inv = 1.f / den;                 // deg >= 1 (self-loop)
            const float* bb = b1 + h * NC1;
            const float* w2 = W2 + h * NC1;
            float p = 0.f;
#pragma unroll
            for (int c = 0; c < NC1; ++c) {
                float o = num[c] * inv + bb[c];
                o = o > 0.f ? o : expm1f(o);       // elu
                p += o * w2[c];
            }
            partial = p;
        }
    }
    spart[tid] = partial;
    __syncthreads();
    if (tid < NPB) {
        int n = node0 + tid;
        if (n < N) {
            float acc = 0.f;
#pragma unroll
            for (int h = 0; h < NH1; ++h) acc += spart[tid * NH1 + h];
            hl2[n] = acc;
            a_src2[n] = acc * att_s2[0];
            a_dst2[n] = acc * att_d2[0];
        }
    }
}

// ---------------- layer 2 aggregation: one thread per node ----------------
__global__ void k_agg2(const int* __restrict__ row, const int* __restrict__ csr_src,
                       const float* __restrict__ a_src2, const float* __restrict__ a_dst2,
                       const float* __restrict__ hl2, const float* __restrict__ b2,
                       float* __restrict__ out, int N) {
    int n = blockIdx.x * blockDim.x + threadIdx.x;
    if (n >= N) return;
    float ad = a_dst2[n];
    float den = 0.f, num = 0.f;
    int beg = row[n], end = row[n + 1];
    int i = beg;
    for (; i + 3 < end; i += 4) {
        int s0 = csr_src[i], s1 = csr_src[i + 1], s2 = csr_src[i + 2], s3 = csr_src[i + 3];
        float v0 = a_src2[s0] + ad, v1 = a_src2[s1] + ad;
        float v2 = a_src2[s2] + ad, v3 = a_src2[s3] + ad;
        float g0 = hl2[s0], g1 = hl2[s1], g2 = hl2[s2], g3 = hl2[s3];
        v0 = v0 > 0.f ? v0 : 0.2f * v0;
        v1 = v1 > 0.f ? v1 : 0.2f * v1;
        v2 = v2 > 0.f ? v2 : 0.2f * v2;
        v3 = v3 > 0.f ? v3 : 0.2f * v3;
        float w0 = __expf(v0), w1 = __expf(v1), w2 = __expf(v2), w3 = __expf(v3);
        den += (w0 + w1) + (w2 + w3);
        num += (w0 * g0 + w1 * g1) + (w2 * g2 + w3 * g3);
    }
    for (; i < end; ++i) {
        int s = csr_src[i];
        float v = a_src2[s] + ad;
        v = v > 0.f ? v : 0.2f * v;
        float w = __expf(v);
        den += w;
        num += w * hl2[s];
    }
    out[n] = num / den + b2[0];
}

extern "C" void kernel_launch(void* const* d_in, const int* in_sizes, int n_in,
                              void* d_out, int out_size, void* d_ws, size_t ws_size,
                              hipStream_t stream) {
    const float* x        = (const float*)d_in[0];
    const int*   ei       = (const int*)d_in[1];
    const float* W1       = (const float*)d_in[2];
    const float* att_src1 = (const float*)d_in[3];
    const float* att_dst1 = (const float*)d_in[4];
    const float* b1       = (const float*)d_in[5];
    const float* W2       = (const float*)d_in[6];
    const float* att_src2 = (const float*)d_in[7];
    const float* att_dst2 = (const float*)d_in[8];
    const float* b2       = (const float*)d_in[9];
    float* out = (float*)d_out;

    const int N  = in_sizes[0] / IN_F;   // 100000
    const int E  = in_sizes[1] / 2;      // 1600000
    const int EN = E + N;                // with self-loops

    // workspace layout (4-byte slots)
    float* ws      = (float*)d_ws;
    h16*   h1h     = (h16*)ws;                         // N*F1 halves (N*F1/2 slots)
    float* a_src1  = ws + (size_t)N * F1 / 2;          // N*NH1
    float* a_dst1  = a_src1 + (size_t)N * NH1;         // N*NH1
    float* hl2     = a_dst1 + (size_t)N * NH1;         // N
    float* a_src2  = hl2 + N;                          // N
    float* a_dst2  = a_src2 + N;                       // N
    int*   deg     = (int*)(a_dst2 + N);               // N
    int*   pos     = deg + N;                          // EN
    int*   row     = pos + EN;                         // N+1
    int*   bsum    = row + (N + 1);                    // 256
    int*   csr_src = bsum + 256;                       // EN

    const int B = 256;
    const int nScanBlocks = (N + SCAN_ELEMS - 1) / SCAN_ELEMS;   // 98
    const int nchunk = 128;                                      // fill chunks

    // ---- CSR build ----
    hipMemsetAsync(deg, 0, (size_t)N * sizeof(int), stream);
    k_degpos<<<(EN + B - 1) / B, B, 0, stream>>>(ei, deg, pos, E, EN);
    k_scan1<<<nScanBlocks, SCAN_T, 0, stream>>>(deg, bsum, N);
    k_scan2<<<1, SCAN_T, 0, stream>>>(bsum, nScanBlocks);
    k_scan3<<<nScanBlocks, SCAN_T, 0, stream>>>(deg, bsum, row, N, EN);
    k_fill <<<nchunk * 8, B, 0, stream>>>(ei, row, pos, csr_src, E, EN, N, nchunk);

    // ---- layer 1 (+ fused layer-2 projection) ----
    k_gemm1<<<(N + BN - 1) / BN, 256, 0, stream>>>(x, W1, att_src1, att_dst1,
                                                   h1h, a_src1, a_dst1, N);
    k_agg1 <<<(N + NPB - 1) / NPB, 256, 0, stream>>>(row, csr_src, a_src1, a_dst1,
                                                     h1h, b1, W2, att_src2, att_dst2,
                                                     hl2, a_src2, a_dst2, N);

    // ---- layer 2 ----
    k_agg2 <<<(N + B - 1) / B, B, 0, stream>>>(row, csr_src, a_src2, a_dst2, hl2, b2, out, N);
}

// Round 5
// 345.094 us; speedup vs baseline: 12.2755x; 1.0703x over previous
//
#include <hip/hip_runtime.h>
#include <math.h>

#define IN_F 67
#define F1   80   // H1*C1
#define NH1  10
#define NC1  8

#define SCAN_T     256
#define SCAN_ELEMS 1024   // elements per scan block (4 per thread)

#define BN  128           // nodes per GEMM block
#define NPB 25            // nodes per agg1 block (25*10 = 250 active threads)
#define PKS 96            // packed row stride in h16 (192 B = 3 cache lines)

typedef _Float16 h16;
typedef h16 h16x2 __attribute__((ext_vector_type(2)));
typedef h16 h16x8 __attribute__((ext_vector_type(8)));

// ---------------- CSR build: degree histogram + within-segment position ----
__global__ void k_degpos(const int* __restrict__ ei, int* __restrict__ deg,
                         int* __restrict__ pos, int E, int EN) {
    int e = blockIdx.x * blockDim.x + threadIdx.x;
    if (e >= EN) return;
    int d = (e < E) ? ei[E + e] : (e - E);
    pos[e] = atomicAdd(&deg[d], 1);
}

// ---------------- scan level 1: per-block sums ----------------
__global__ void k_scan1(const int* __restrict__ deg, int* __restrict__ bsum, int N) {
    __shared__ int sdata[SCAN_T];
    int base = blockIdx.x * SCAN_ELEMS;
    int sum = 0;
    for (int i = threadIdx.x; i < SCAN_ELEMS; i += SCAN_T) {
        int g = base + i;
        sum += (g < N) ? deg[g] : 0;
    }
    sdata[threadIdx.x] = sum;
    __syncthreads();
    for (int o = SCAN_T / 2; o > 0; o >>= 1) {
        if (threadIdx.x < o) sdata[threadIdx.x] += sdata[threadIdx.x + o];
        __syncthreads();
    }
    if (threadIdx.x == 0) bsum[blockIdx.x] = sdata[0];
}

// ---------------- scan level 2: exclusive scan of block sums (nb <= 256) ----
__global__ void k_scan2(int* __restrict__ bsum, int nb) {
    __shared__ int s[SCAN_T];
    int t = threadIdx.x;
    int v = (t < nb) ? bsum[t] : 0;
    s[t] = v;
    __syncthreads();
    for (int o = 1; o < SCAN_T; o <<= 1) {
        int u = (t >= o) ? s[t - o] : 0;
        __syncthreads();
        s[t] += u;
        __syncthreads();
    }
    if (t < nb) bsum[t] = s[t] - v;   // exclusive
}

// ---------------- scan level 3: per-element exclusive scan -> row ----------
__global__ void k_scan3(const int* __restrict__ deg, const int* __restrict__ bsum,
                        int* __restrict__ row, int N, int EN) {
    __shared__ int sdata[SCAN_T];
    int base = blockIdx.x * SCAN_ELEMS;
    int g0 = base + threadIdx.x * 4;
    int v[4];
    int s = 0;
#pragma unroll
    for (int j = 0; j < 4; ++j) {
        int g = g0 + j;
        v[j] = (g < N) ? deg[g] : 0;
        s += v[j];
    }
    sdata[threadIdx.x] = s;
    __syncthreads();
    for (int o = 1; o < SCAN_T; o <<= 1) {
        int u = (threadIdx.x >= o) ? sdata[threadIdx.x - o] : 0;
        __syncthreads();
        sdata[threadIdx.x] += u;
        __syncthreads();
    }
    int excl = sdata[threadIdx.x] - s + bsum[blockIdx.x];
#pragma unroll
    for (int j = 0; j < 4; ++j) {
        int g = g0 + j;
        if (g < N) { row[g] = excl; excl += v[j]; }
    }
    if (blockIdx.x == 0 && threadIdx.x == 0) row[N] = EN;
}

// ---------------- CSR fill: atomic-free, XCD-partitioned by dst range ------
__global__ void k_fill(const int* __restrict__ ei, const int* __restrict__ row,
                       const int* __restrict__ pos, int* __restrict__ csr_src,
                       int E, int EN, int N, int nchunk) {
    int xcd = blockIdx.x & 7;
    int cb  = blockIdx.x >> 3;
    int range = (N + 7) >> 3;
    int lo = xcd * range;
    int hi = lo + range;
    int stride = nchunk * blockDim.x;
    for (int e = cb * blockDim.x + threadIdx.x; e < EN; e += stride) {
        int s, d;
        if (e < E) { d = ei[E + e]; s = ei[e]; } else { d = e - E; s = d; }
        if (d >= lo && d < hi) {
            csr_src[row[d] + pos[e]] = s;
        }
    }
}

// ---------------- layer 1: fused GEMM + attention logits, packed rows ------
// pk row (PKS=96 h16 = 192 B): [0..79]=h fp16, [80..89]=a_src fp16, pad.
__global__ __launch_bounds__(256, 2)
void k_gemm1(const float* __restrict__ x, const float* __restrict__ W,
             const float* __restrict__ att_s, const float* __restrict__ att_d,
             h16* __restrict__ pk, float* __restrict__ a_dst, int N) {
    __shared__ float sW[IN_F * F1];       // 21440 B
    __shared__ float sbuf[BN * 81];       // x-phase stride 69, h-phase stride 81

    const int tid = threadIdx.x;
    const int node0 = blockIdx.x * BN;

    for (int i = tid; i < IN_F * F1; i += 256) sW[i] = W[i];
    for (int i = tid; i < BN * IN_F; i += 256) {
        int n = i / IN_F;
        int k = i - n * IN_F;
        int gn = node0 + n;
        sbuf[n * 69 + k] = (gn < N) ? x[gn * IN_F + k] : 0.f;
    }
    __syncthreads();

    const int tx = tid & 15, ty = tid >> 4;
    float acc[8][5];
#pragma unroll
    for (int i = 0; i < 8; ++i)
#pragma unroll
        for (int j = 0; j < 5; ++j) acc[i][j] = 0.f;

    const float* sxp = sbuf + ty * 8 * 69;
    const float* swp = sW + tx * 5;
    for (int k = 0; k < IN_F; ++k) {
        float b0 = swp[k * F1 + 0];
        float b1 = swp[k * F1 + 1];
        float b2 = swp[k * F1 + 2];
        float b3 = swp[k * F1 + 3];
        float b4 = swp[k * F1 + 4];
#pragma unroll
        for (int i = 0; i < 8; ++i) {
            float a = sxp[i * 69 + k];
            acc[i][0] += a * b0;
            acc[i][1] += a * b1;
            acc[i][2] += a * b2;
            acc[i][3] += a * b3;
            acc[i][4] += a * b4;
        }
    }

    __syncthreads();
#pragma unroll
    for (int i = 0; i < 8; ++i)
#pragma unroll
        for (int j = 0; j < 5; ++j)
            sbuf[(ty * 8 + i) * 81 + tx * 5 + j] = acc[i][j];
    __syncthreads();

    // packed h write-out as fp16 pairs (4 B stores)
    for (int idx = tid; idx < BN * (F1 / 2); idx += 256) {
        int n = idx / (F1 / 2);
        int p = idx - n * (F1 / 2);
        int gn = node0 + n;
        if (gn < N) {
            h16x2 v;
            v.x = (h16)sbuf[n * 81 + 2 * p];
            v.y = (h16)sbuf[n * 81 + 2 * p + 1];
            *(h16x2*)(pk + (size_t)gn * PKS + 2 * p) = v;
        }
    }
    // attention logits: a_src packed (fp16) into row; a_dst fp32 separate
    for (int t = tid; t < BN * NH1; t += 256) {
        int n = t / NH1;
        int h = t - n * NH1;
        int gn = node0 + n;
        if (gn < N) {
            const float* hr = sbuf + n * 81 + h * NC1;
            float s = 0.f, d = 0.f;
#pragma unroll
            for (int c = 0; c < NC1; ++c) {
                float v = hr[c];
                s += v * att_s[h * NC1 + c];
                d += v * att_d[h * NC1 + c];
            }
            pk[(size_t)gn * PKS + F1 + h] = (h16)s;
            a_dst[gn * NH1 + h] = d;
        }
    }
}

// ---------------- layer 1 aggregation FUSED with ELU + layer-2 projection --
__global__ __launch_bounds__(256)
void k_agg1(const int* __restrict__ row, const int* __restrict__ csr_src,
            const h16* __restrict__ pk, const float* __restrict__ a_dst,
            const float* __restrict__ b1, const float* __restrict__ W2,
            const float* __restrict__ att_s2, const float* __restrict__ att_d2,
            float2* __restrict__ hs2, float* __restrict__ a_dst2, int N) {
    __shared__ float spart[256];
    const int tid = threadIdx.x;
    const int node0 = blockIdx.x * NPB;

    float partial = 0.f;
    if (tid < NPB * NH1) {
        int n_l = tid / NH1;
        int h = tid - n_l * NH1;
        int n = node0 + n_l;
        if (n < N) {
            int beg = row[n], end = row[n + 1];
            float ad = a_dst[n * NH1 + h];
            float den = 0.f;
            float num[NC1];
#pragma unroll
            for (int c = 0; c < NC1; ++c) num[c] = 0.f;

            int i = beg;
            // 8-wide unroll: 8 independent 16B gathers in flight per lane
            for (; i + 7 < end; i += 8) {
                int sv[8];
#pragma unroll
                for (int j = 0; j < 8; ++j) sv[j] = csr_src[i + j];
                h16x8 q[8];
                float a[8];
#pragma unroll
                for (int j = 0; j < 8; ++j) {
                    const h16* rp = pk + (size_t)sv[j] * PKS;
                    q[j] = *(const h16x8*)(rp + h * NC1);
                    a[j] = (float)rp[F1 + h];
                }
#pragma unroll
                for (int j = 0; j < 8; ++j) {
                    float v = a[j] + ad;
                    v = v > 0.f ? v : 0.2f * v;
                    float w = __expf(v);
                    den += w;
#pragma unroll
                    for (int c = 0; c < NC1; ++c) num[c] += w * (float)q[j][c];
                }
            }
            for (; i + 3 < end; i += 4) {
                int sv[4];
#pragma unroll
                for (int j = 0; j < 4; ++j) sv[j] = csr_src[i + j];
                h16x8 q[4];
                float a[4];
#pragma unroll
                for (int j = 0; j < 4; ++j) {
                    const h16* rp = pk + (size_t)sv[j] * PKS;
                    q[j] = *(const h16x8*)(rp + h * NC1);
                    a[j] = (float)rp[F1 + h];
                }
#pragma unroll
                for (int j = 0; j < 4; ++j) {
                    float v = a[j] + ad;
                    v = v > 0.f ? v : 0.2f * v;
                    float w = __expf(v);
                    den += w;
#pragma unroll
                    for (int c = 0; c < NC1; ++c) num[c] += w * (float)q[j][c];
                }
            }
            for (; i < end; ++i) {
                const h16* rp = pk + (size_t)csr_src[i] * PKS;
                h16x8 q = *(const h16x8*)(rp + h * NC1);
                float v = (float)rp[F1 + h] + ad;
                v = v > 0.f ? v : 0.2f * v;
                float w = __expf(v);
                den += w;
#pragma unroll
                for (int c = 0; c < NC1; ++c) num[c] += w * (float)q[c];
            }
            float inv = 1.f / den;                 // deg >= 1 (self-loop)
            const float* bb = b1 + h * NC1;
            const float* w2 = W2 + h * NC1;
            float p = 0.f;
#pragma unroll
            for (int c = 0; c < NC1; ++c) {
                float o = num[c] * inv + bb[c];
                o = o > 0.f ? o : expm1f(o);       // elu
                p += o * w2[c];
            }
            partial = p;
        }
    }
    spart[tid] = partial;
    __syncthreads();
    if (tid < NPB) {
        int n = node0 + tid;
        if (n < N) {
            float acc = 0.f;
#pragma unroll
            for (int h = 0; h < NH1; ++h) acc += spart[tid * NH1 + h];
            float2 v;
            v.x = acc;                  // hl2
            v.y = acc * att_s2[0];      // a_src2
            hs2[n] = v;
            a_dst2[n] = acc * att_d2[0];
        }
    }
}

// ---------------- layer 2 aggregation: one thread per node ----------------
// gathers packed {hl2, a_src2} float2 -> 1 cache line per edge
__global__ void k_agg2(const int* __restrict__ row, const int* __restrict__ csr_src,
                       const float2* __restrict__ hs2, const float* __restrict__ a_dst2,
                       const float* __restrict__ b2, float* __restrict__ out, int N) {
    int n = blockIdx.x * blockDim.x + threadIdx.x;
    if (n >= N) return;
    float ad = a_dst2[n];
    float den = 0.f, num = 0.f;
    int beg = row[n], end = row[n + 1];
    int i = beg;
    for (; i + 7 < end; i += 8) {
        int sv[8];
#pragma unroll
        for (int j = 0; j < 8; ++j) sv[j] = csr_src[i + j];
        float2 g[8];
#pragma unroll
        for (int j = 0; j < 8; ++j) g[j] = hs2[sv[j]];
#pragma unroll
        for (int j = 0; j < 8; ++j) {
            float v = g[j].y + ad;
            v = v > 0.f ? v : 0.2f * v;
            float w = __expf(v);
            den += w;
            num += w * g[j].x;
        }
    }
    for (; i < end; ++i) {
        float2 g = hs2[csr_src[i]];
        float v = g.y + ad;
        v = v > 0.f ? v : 0.2f * v;
        float w = __expf(v);
        den += w;
        num += w * g.x;
    }
    out[n] = num / den + b2[0];
}

extern "C" void kernel_launch(void* const* d_in, const int* in_sizes, int n_in,
                              void* d_out, int out_size, void* d_ws, size_t ws_size,
                              hipStream_t stream) {
    const float* x        = (const float*)d_in[0];
    const int*   ei       = (const int*)d_in[1];
    const float* W1       = (const float*)d_in[2];
    const float* att_src1 = (const float*)d_in[3];
    const float* att_dst1 = (const float*)d_in[4];
    const float* b1       = (const float*)d_in[5];
    const float* W2       = (const float*)d_in[6];
    const float* att_src2 = (const float*)d_in[7];
    const float* att_dst2 = (const float*)d_in[8];
    const float* b2       = (const float*)d_in[9];
    float* out = (float*)d_out;

    const int N  = in_sizes[0] / IN_F;   // 100000
    const int E  = in_sizes[1] / 2;      // 1600000
    const int EN = E + N;                // with self-loops

    // workspace layout (4-byte slots)
    float*  ws      = (float*)d_ws;
    h16*    pk      = (h16*)ws;                        // N*PKS h16 = N*48 floats
    float*  a_dst1  = ws + (size_t)N * (PKS / 2);      // N*NH1
    float2* hs2     = (float2*)(a_dst1 + (size_t)N * NH1);  // N float2
    float*  a_dst2  = (float*)(hs2 + N);               // N
    int*    deg     = (int*)(a_dst2 + N);              // N
    int*    pos     = deg + N;                         // EN
    int*    row     = pos + EN;                        // N+1
    int*    bsum    = row + (N + 1);                   // 256
    int*    csr_src = bsum + 256;                      // EN

    const int B = 256;
    const int nScanBlocks = (N + SCAN_ELEMS - 1) / SCAN_ELEMS;   // 98
    const int nchunk = 128;                                      // fill chunks

    // ---- CSR build ----
    hipMemsetAsync(deg, 0, (size_t)N * sizeof(int), stream);
    k_degpos<<<(EN + B - 1) / B, B, 0, stream>>>(ei, deg, pos, E, EN);
    k_scan1<<<nScanBlocks, SCAN_T, 0, stream>>>(deg, bsum, N);
    k_scan2<<<1, SCAN_T, 0, stream>>>(bsum, nScanBlocks);
    k_scan3<<<nScanBlocks, SCAN_T, 0, stream>>>(deg, bsum, row, N, EN);
    k_fill <<<nchunk * 8, B, 0, stream>>>(ei, row, pos, csr_src, E, EN, N, nchunk);

    // ---- layer 1 (+ fused layer-2 projection) ----
    k_gemm1<<<(N + BN - 1) / BN, 256, 0, stream>>>(x, W1, att_src1, att_dst1,
                                                   pk, a_dst1, N);
    k_agg1 <<<(N + NPB - 1) / NPB, 256, 0, stream>>>(row, csr_src, pk, a_dst1,
                                                     b1, W2, att_src2, att_dst2,
                                                     hs2, a_dst2, N);

    // ---- layer 2 ----
    k_agg2 <<<(N + B - 1) / B, B, 0, stream>>>(row, csr_src, hs2, a_dst2, b2, out, N);
}